// Round 1
// baseline (97.716 us; speedup 1.0000x reference)
//
#include <hip/hip_runtime.h>

// Problem shape (fixed by setup_inputs):
//   query_points  [4, 4096, 3] fp32
//   scene_pc      [4, 8192, 3] fp32
//   scene_pc_feats[4, 8192, 1] fp32
//   out           [4, 4096, 1] fp32
// out[b,n] = sum_m exp(-||qp[b,n,:2]-sp[b,m,:2]||) * f[b,m] / sum_m exp(-...)

#define B_DIM   4
#define N_DIM   4096
#define M_DIM   8192
#define NQ      (B_DIM * N_DIM)          // 16384 queries
#define QB      256                      // queries (threads) per block
#define MS      16                       // M splits
#define CHUNK   (M_DIM / MS)             // 512 scene points per block

static_assert(CHUNK % 4 == 0, "chunk must be float4-divisible");

__device__ __forceinline__ void accum_pt(float qx, float qy, float x, float y,
                                         float f, float& sw, float& swf) {
    float dx = qx - x;
    float dy = qy - y;
    float d2 = fmaf(dy, dy, dx * dx);
    // coords pre-scaled by log2(e): exp(-alpha*d) == exp2(-sqrt(d2_scaled))
    float w = __builtin_amdgcn_exp2f(-__builtin_amdgcn_sqrtf(d2));
    sw += w;
    swf = fmaf(w, f, swf);
}

__global__ __launch_bounds__(QB) void mfe_partial(
    const float* __restrict__ qp,     // [B,N,3]
    const float* __restrict__ sp,     // [B,M,3]
    const float* __restrict__ feats,  // [B,M,1]
    float* __restrict__ acc_swf,      // [NQ]
    float* __restrict__ acc_sw)       // [NQ]
{
    __shared__ float xs[CHUNK];
    __shared__ float ys[CHUNK];
    __shared__ float fs[CHUNK];

    const float LOG2E = 1.4426950408889634f;

    const int tid    = threadIdx.x;
    const int qgroup = blockIdx.x;            // 0 .. NQ/QB-1 (64)
    const int split  = blockIdx.y;            // 0 .. MS-1
    const int qid    = qgroup * QB + tid;     // global query id (b-major flat)
    const int b      = qgroup / (N_DIM / QB); // 16 groups per batch

    // Stage scene chunk into LDS (SoA), pre-scaled by log2e.
    const int mbase = b * M_DIM + split * CHUNK;
    #pragma unroll
    for (int i = tid; i < CHUNK; i += QB) {
        const int m = mbase + i;
        xs[i] = sp[m * 3 + 0] * LOG2E;
        ys[i] = sp[m * 3 + 1] * LOG2E;
        fs[i] = feats[m];
    }
    __syncthreads();

    const float qx = qp[qid * 3 + 0] * LOG2E;
    const float qy = qp[qid * 3 + 1] * LOG2E;

    float sw = 0.0f, swf = 0.0f;

    const float4* x4 = (const float4*)xs;
    const float4* y4 = (const float4*)ys;
    const float4* f4 = (const float4*)fs;

    #pragma unroll 4
    for (int j = 0; j < CHUNK / 4; ++j) {
        const float4 X = x4[j];   // wave-uniform address -> LDS broadcast
        const float4 Y = y4[j];
        const float4 F = f4[j];
        accum_pt(qx, qy, X.x, Y.x, F.x, sw, swf);
        accum_pt(qx, qy, X.y, Y.y, F.y, sw, swf);
        accum_pt(qx, qy, X.z, Y.z, F.z, sw, swf);
        accum_pt(qx, qy, X.w, Y.w, F.w, sw, swf);
    }

    atomicAdd(&acc_swf[qid], swf);
    atomicAdd(&acc_sw[qid], sw);
}

__global__ __launch_bounds__(256) void mfe_div(
    const float* __restrict__ acc_swf,
    const float* __restrict__ acc_sw,
    float* __restrict__ out)
{
    const int i = blockIdx.x * blockDim.x + threadIdx.x;
    if (i < NQ) out[i] = acc_swf[i] / acc_sw[i];
}

extern "C" void kernel_launch(void* const* d_in, const int* in_sizes, int n_in,
                              void* d_out, int out_size, void* d_ws, size_t ws_size,
                              hipStream_t stream) {
    const float* qp    = (const float*)d_in[0];
    const float* sp    = (const float*)d_in[1];
    const float* feats = (const float*)d_in[2];
    float* out = (float*)d_out;

    float* acc_swf = (float*)d_ws;          // [NQ]
    float* acc_sw  = acc_swf + NQ;          // [NQ]

    // ws is re-poisoned to 0xAA before every launch — zero the accumulators.
    hipMemsetAsync(d_ws, 0, 2 * NQ * sizeof(float), stream);

    dim3 grid(NQ / QB, MS);
    mfe_partial<<<grid, QB, 0, stream>>>(qp, sp, feats, acc_swf, acc_sw);
    mfe_div<<<NQ / 256, 256, 0, stream>>>(acc_swf, acc_sw, out);
}

// Round 2
// 90.880 us; speedup vs baseline: 1.0752x; 1.0752x over previous
//
#include <hip/hip_runtime.h>

// Problem shape (fixed):
//   query_points  [4, 4096, 3] fp32
//   scene_pc      [4, 8192, 3] fp32
//   scene_pc_feats[4, 8192, 1] fp32
//   out           [4, 4096, 1] fp32
// out[b,n] = sum_m exp(-||qp[b,n,:2]-sp[b,m,:2]||) * f[b,m] / sum_m exp(-...)
//
// Fully fused single kernel: block = 32 queries x 16 M-slices (512 thr),
// M staged through LDS in 2048-pt chunks as float4 {x, y, L2*(x^2+y^2), f},
// per-pair math reduced to 5 full-rate VALU + sqrt + exp2 via
//   L2*d2 = a*x + b*y + X2' + Q2',  a=-2*L2*qx, b=-2*L2*qy  (L2 = log2e^2)
// so w = exp2(-sqrt(L2*d2)) = exp(-d). abs/neg fold into sqrt/exp2 modifiers.

#define B_DIM   4
#define N_DIM   4096
#define M_DIM   8192
#define NQ      (B_DIM * N_DIM)       // 16384
#define QPB     32                    // queries per block
#define SLICES  16                    // M-slices per block
#define THREADS (QPB * SLICES)        // 512
#define CHUNK   2048                  // scene points staged per iteration
#define NCHUNK  (M_DIM / CHUNK)       // 4
#define PPT     (CHUNK / THREADS)     // 4 staging points per thread
#define IPT     (CHUNK / SLICES)      // 128 inner points per thread per chunk

__global__ __launch_bounds__(THREADS) void mfe_fused(
    const float* __restrict__ qp,     // [B,N,3]
    const float* __restrict__ sp,     // [B,M,3]
    const float* __restrict__ feats,  // [B,M,1]
    float* __restrict__ out)          // [B,N,1]
{
    __shared__ float4 pts[CHUNK];          // 32 KB: x, y, X2', f
    __shared__ float  red[2 * THREADS];    // 4 KB reduction scratch

    const float L2 = 2.0813689810056077f;  // (log2 e)^2

    const int tid = threadIdx.x;
    const int q   = tid & (QPB - 1);       // query within block
    const int s   = tid >> 5;              // slice; wave = 2 slices -> 2-way LDS broadcast (free)
    const int qid = blockIdx.x * QPB + q;
    const int b   = qid >> 12;             // qid / N_DIM
    const int mb0 = b * M_DIM;

    const float qx = qp[qid * 3 + 0];
    const float qy = qp[qid * 3 + 1];
    const float ca = -2.0f * L2 * qx;
    const float cb = -2.0f * L2 * qy;
    const float Q2 = L2 * (qx * qx + qy * qy);

    float sw0 = 0.f, sw1 = 0.f, swf0 = 0.f, swf1 = 0.f;

    for (int c = 0; c < NCHUNK; ++c) {
        const int mbase = mb0 + c * CHUNK;
        __syncthreads();                   // protect pts[] reuse
        #pragma unroll
        for (int k = 0; k < PPT; ++k) {
            const int i = tid + k * THREADS;
            const int m = mbase + i;
            const float x = sp[m * 3 + 0];
            const float y = sp[m * 3 + 1];
            const float f = feats[m];
            pts[i] = make_float4(x, y, L2 * fmaf(x, x, y * y), f);
        }
        __syncthreads();

        const float4* __restrict__ p = pts + s * IPT;
        #pragma unroll 8
        for (int j = 0; j < IPT; j += 2) {
            const float4 P0 = p[j];
            const float4 P1 = p[j + 1];
            const float d0 = fmaf(ca, P0.x, fmaf(cb, P0.y, P0.z)) + Q2;
            const float d1 = fmaf(ca, P1.x, fmaf(cb, P1.y, P1.z)) + Q2;
            const float w0 = __builtin_amdgcn_exp2f(-__builtin_amdgcn_sqrtf(fabsf(d0)));
            const float w1 = __builtin_amdgcn_exp2f(-__builtin_amdgcn_sqrtf(fabsf(d1)));
            sw0  += w0;
            sw1  += w1;
            swf0 = fmaf(w0, P0.w, swf0);
            swf1 = fmaf(w1, P1.w, swf1);
        }
    }

    // Per-query reduction over 16 slices, then normalize and store.
    red[tid]           = sw0 + sw1;
    red[THREADS + tid] = swf0 + swf1;
    __syncthreads();
    if (tid < QPB) {
        float sw = 0.f, swf = 0.f;
        #pragma unroll
        for (int k = 0; k < SLICES; ++k) {
            sw  += red[k * QPB + tid];              // lane q -> bank q, conflict-free
            swf += red[THREADS + k * QPB + tid];
        }
        out[blockIdx.x * QPB + tid] = swf / sw;
    }
}

extern "C" void kernel_launch(void* const* d_in, const int* in_sizes, int n_in,
                              void* d_out, int out_size, void* d_ws, size_t ws_size,
                              hipStream_t stream) {
    const float* qp    = (const float*)d_in[0];
    const float* sp    = (const float*)d_in[1];
    const float* feats = (const float*)d_in[2];
    float* out = (float*)d_out;

    mfe_fused<<<NQ / QPB, THREADS, 0, stream>>>(qp, sp, feats, out);
}